// Round 8
// baseline (227.105 us; speedup 1.0000x reference)
//
#include <hip/hip_runtime.h>

constexpr int kC = 147, kH = 64, kBPM = 32;

typedef __attribute__((ext_vector_type(8)))  short bf16x8;   // MFMA A/B frag
typedef __attribute__((ext_vector_type(4)))  float f32x4;    // 16x16 C/D frag
typedef __attribute__((ext_vector_type(16))) float f32x16;   // 32x32 C/D frag
typedef __attribute__((ext_vector_type(2)))  unsigned u32x2;
typedef __attribute__((ext_vector_type(4)))  unsigned u32x4;

__device__ __forceinline__ short f2bf(float f) {             // RNE float->bf16
    unsigned u = __builtin_bit_cast(unsigned, f);
    u += 0x7fffu + ((u >> 16) & 1u);
    return (short)(u >> 16);
}
// Packed RNE f32x2 -> bf16x2 (single VALU op; bit-identical to f2bf pairs).
__device__ __forceinline__ unsigned cvt_pk(float lo, float hi) {
    unsigned r;
    asm("v_cvt_pk_bf16_f32 %0, %1, %2" : "=v"(r) : "v"(lo), "v"(hi));
    return r;
}
#define MFMA16(a,b,c) __builtin_amdgcn_mfma_f32_16x16x32_bf16((a),(b),(c),0,0,0)
#define MFMA32(a,b,c) __builtin_amdgcn_mfma_f32_32x32x16_bf16((a),(b),(c),0,0,0)

// Softmax in base 2: Wq and q-bias pre-scaled by 0.25*log2(e); P = 2^s.
#if __has_builtin(__builtin_amdgcn_exp2f)
  #define EXP2(x) __builtin_amdgcn_exp2f(x)
#else
  #define EXP2(x) __expf((x) * 0.6931471805599453f)   // exact: e^(x ln2) = 2^x
#endif
constexpr float kQScale = 0.25f * 1.4426950408889634f;

// ===================== prep: W -> bf16 frag layouts + combined k-bias =======
// wt layout (shorts): [0) WtQ[c][160], [10240) WtK, [20480) WtV  (c=64, k=160,
// zero-padded past 147; WtQ pre-scaled by kQScale);  [30720) WtO[n=160][k=64].
// kbc[b][c] = bk[c] + bb[c] + bpm_emb[b]@Wb  (exact order of the fused bias).
__global__ __launch_bounds__(128) void prep_kernel(
    const float* __restrict__ bpm_emb,
    const float* __restrict__ Wq, const float* __restrict__ Wk,
    const float* __restrict__ Wv, const float* __restrict__ Wb,
    const float* __restrict__ bk, const float* __restrict__ bb,
    const float* __restrict__ Wo,
    short* __restrict__ wt, float* __restrict__ kbc)
{
    const int bid = blockIdx.x, tid = threadIdx.x;
    if (bid < 256) {
        if (tid < kH) {
            const int c = tid;
            float a = bk[c];
            a += bb[c];
            #pragma unroll
            for (int j = 0; j < kBPM; ++j)
                a = fmaf(bpm_emb[bid * kBPM + j], Wb[j * kH + c], a);
            kbc[bid * kH + c] = a;
        }
    } else if (bid < 259) {
        const int m = bid - 256;
        const float* W = (m == 0) ? Wq : (m == 1) ? Wk : Wv;
        const float scale = (m == 0) ? kQScale : 1.f;
        short* dst = wt + m * 10240;
        for (int idx = tid; idx < 64 * 160; idx += 128) {
            const int c = idx / 160, k = idx - c * 160;
            dst[idx] = f2bf((k < kC) ? W[k * kH + c] * scale : 0.f);
        }
    } else {
        short* dst = wt + 3 * 10240;
        for (int idx = tid; idx < 160 * 64; idx += 128) {
            const int n = idx >> 6, k = idx & 63;
            dst[idx] = f2bf((n < kC) ? Wo[k * kC + n] : 0.f);
        }
    }
}

// ============================ main: 2 blocks/CU =============================
// 512 blocks = (batch, q-half of 128 rows); 512 threads = 8 waves.
// LDS exactly 80 KB -> two blocks co-resident per CU; 8-wave barrier scope
// with an independent block filling stalls.  K,V computed for all 256 rows
// (duplicated across the pair; MFMA is ~10% busy), Q for own 128.
// W-frags are 16B L2 loads from the prep layouts: no Ws LDS, no staging
// barriers -> 2 barriers total.  All LDS arrays XOR-swizzled:
// phys_col = col ^ ((row&7)<<3)   (8-short granule, b128/u32x2 compatible).
__global__ __launch_bounds__(512, 4) void fused_kernel(
    const float* __restrict__ pose,
    const float* __restrict__ bq, const float* __restrict__ bv,
    const short* __restrict__ wt, const float* __restrict__ kbc,
    const float* __restrict__ bo, float* __restrict__ out)
{
    __shared__ __align__(16) short qs[128 * 64];   // 16 KB  q, later X
    __shared__ __align__(16) short ks_[256 * 64];  // 32 KB  k (+combined bias)
    __shared__ __align__(16) short vt[64 * 256];   // 32 KB  V^T: [d][j]

    const int tid = threadIdx.x;
    const int w = tid >> 6, lane = tid & 63;
    const int ll = lane & 15, lq = lane >> 4;
    const int lm = lane & 31, lh = lane >> 5;
    const int b = blockIdx.x >> 1, half = blockIdx.x & 1;
    const size_t pbase = (size_t)b * 256 * kC;
    const short* wtq = wt;
    const short* wtk = wt + 10240;
    const short* wtv = wt + 20480;
    const short* wto = wt + 30720;

    // ---- projections: pass 0/1 = K+V for rows 0-127 / 128-255 (pf shared);
    //      pass 2 = Q for this block's 128 rows ----
    #pragma unroll
    for (int pass = 0; pass < 3; ++pass) {
        const int row = (pass < 2 ? pass * 128 : half * 128) + w * 16 + ll;
        bf16x8 pf[5];
        {
            const float* prow = pose + pbase + (size_t)row * kC;
            #pragma unroll
            for (int ksp = 0; ksp < 5; ++ksp) {
                const int c0 = ksp * 32 + lq * 8;
                float v[8];
                if (c0 + 8 <= kC) {
                    const float4 f0 = *(const float4*)(prow + c0);
                    const float4 f1 = *(const float4*)(prow + c0 + 4);
                    v[0]=f0.x; v[1]=f0.y; v[2]=f0.z; v[3]=f0.w;
                    v[4]=f1.x; v[5]=f1.y; v[6]=f1.z; v[7]=f1.w;
                } else {
                    #pragma unroll
                    for (int e = 0; e < 8; ++e) v[e] = (c0 + e < kC) ? prow[c0 + e] : 0.f;
                }
                const u32x4 t = { cvt_pk(v[0], v[1]), cvt_pk(v[2], v[3]),
                                  cvt_pk(v[4], v[5]), cvt_pk(v[6], v[7]) };
                pf[ksp] = __builtin_bit_cast(bf16x8, t);
            }
        }
        if (pass < 2) {
            f32x4 accK[4], accV[4];
            #pragma unroll
            for (int mt = 0; mt < 4; ++mt) {
                accK[mt] = (f32x4){0.f,0.f,0.f,0.f};
                accV[mt] = (f32x4){0.f,0.f,0.f,0.f};
            }
            #pragma unroll
            for (int ksp = 0; ksp < 5; ++ksp)
                #pragma unroll
                for (int mt = 0; mt < 4; ++mt) {
                    const int off = (mt * 16 + ll) * 160 + ksp * 32 + lq * 8;
                    accK[mt] = MFMA16(*(const bf16x8*)(wtk + off), pf[ksp], accK[mt]);
                    accV[mt] = MFMA16(*(const bf16x8*)(wtv + off), pf[ksp], accV[mt]);
                }
            const int rkey = (row & 7) << 3;
            #pragma unroll
            for (int mt = 0; mt < 4; ++mt) {
                const int c0 = mt * 16 + 4 * lq;
                const float4 kb4 = *(const float4*)(kbc + b * kH + c0);
                const u32x2 pk = { cvt_pk(accK[mt][0] + kb4.x, accK[mt][1] + kb4.y),
                                   cvt_pk(accK[mt][2] + kb4.z, accK[mt][3] + kb4.w) };
                *(u32x2*)(ks_ + row * 64 + (c0 ^ rkey)) = pk;
                const float4 bv4 = *(const float4*)(bv + c0);
                vt[(c0 + 0) * 256 + (row ^ (((c0 + 0) & 7) << 3))] = f2bf(accV[mt][0] + bv4.x);
                vt[(c0 + 1) * 256 + (row ^ (((c0 + 1) & 7) << 3))] = f2bf(accV[mt][1] + bv4.y);
                vt[(c0 + 2) * 256 + (row ^ (((c0 + 2) & 7) << 3))] = f2bf(accV[mt][2] + bv4.z);
                vt[(c0 + 3) * 256 + (row ^ (((c0 + 3) & 7) << 3))] = f2bf(accV[mt][3] + bv4.w);
            }
        } else {
            f32x4 acc[4];
            #pragma unroll
            for (int mt = 0; mt < 4; ++mt) acc[mt] = (f32x4){0.f,0.f,0.f,0.f};
            #pragma unroll
            for (int ksp = 0; ksp < 5; ++ksp)
                #pragma unroll
                for (int mt = 0; mt < 4; ++mt) {
                    const int off = (mt * 16 + ll) * 160 + ksp * 32 + lq * 8;
                    acc[mt] = MFMA16(*(const bf16x8*)(wtq + off), pf[ksp], acc[mt]);
                }
            const int rl = w * 16 + ll;          // local qs row
            const int rkey = (rl & 7) << 3;
            #pragma unroll
            for (int mt = 0; mt < 4; ++mt) {
                const int c0 = mt * 16 + 4 * lq;
                const float4 bq4 = *(const float4*)(bq + c0);
                const float q0b = bq4.x * kQScale, q1b = bq4.y * kQScale;
                const float q2b = bq4.z * kQScale, q3b = bq4.w * kQScale;
                const u32x2 pk = { cvt_pk(acc[mt][0] + q0b, acc[mt][1] + q1b),
                                   cvt_pk(acc[mt][2] + q2b, acc[mt][3] + q3b) };
                *(u32x2*)(qs + rl * 64 + (c0 ^ rkey)) = pk;
            }
        }
    }
    __syncthreads();                            // qs/ks_/vt complete

    // ================= attention: wave = (head, q-quarter of 128) ==========
    // Swapped QK^T (lane = q) + permlane half-exchange: P stays in registers;
    // PV = 32x32x16 MFMA with B=P (col=q=lane).  s32-outer caps live regs.
    const int h = w & 3;
    const int q0 = (w >> 2) * 64;
    const int vrow = h * 16 + (lm & 15);       // lanes 16-31 dup rows (bcast)
    const int vkey = (vrow & 7) << 3;
    const int ckey = (lm & 7) << 3;            // q/k rows ≡ lm (mod 8)
    const f32x16 z16 = {0.f,0.f,0.f,0.f,0.f,0.f,0.f,0.f,
                        0.f,0.f,0.f,0.f,0.f,0.f,0.f,0.f};

    #pragma unroll
    for (int s32 = 0; s32 < 2; ++s32) {
        const int qrow = q0 + s32 * 32 + lm;   // local row; qrow&7 == lm&7
        const bf16x8 qf = *(const bf16x8*)(qs + qrow * 64 + ((h*16 + lh*8) ^ ckey));
        f32x16 oacc = z16;
        float lp = 0.f;
        #pragma unroll 2
        for (int jb = 0; jb < 8; ++jb) {
            const int j0 = jb * 32;
            const bf16x8 kf  = *(const bf16x8*)(ks_ + (j0 + lm) * 64 + ((h*16 + lh*8) ^ ckey));
            const bf16x8 va0 = *(const bf16x8*)(vt + vrow * 256 + ((j0 + lh*8) ^ vkey));
            const bf16x8 va1 = *(const bf16x8*)(vt + vrow * 256 + ((j0 + 16 + lh*8) ^ vkey));
            const f32x16 s = MFMA32(kf, qf, z16);    // S^T: col=q=lm, row=j
            float sum = 0.f;
            unsigned u[8];
            #pragma unroll
            for (int g = 0; g < 4; ++g) {            // j = r + 8g + 4lh
                const float p0 = EXP2(s[4*g + 0]);   // scale folded into Wq
                const float p1 = EXP2(s[4*g + 1]);
                const float p2 = EXP2(s[4*g + 2]);
                const float p3 = EXP2(s[4*g + 3]);
                sum += (p0 + p1) + (p2 + p3);
                u[2*g]   = cvt_pk(p0, p1);
                u[2*g+1] = cvt_pk(p2, p3);
            }
            lp += sum;
            // lane±32 half-exchange -> B-frags with k=j in order (T12)
            unsigned a0 = u[0], a1 = u[1], b0 = u[2], b1 = u[3];
            asm("v_permlane32_swap_b32 %0, %1" : "+v"(a0), "+v"(b0));
            asm("v_permlane32_swap_b32 %0, %1" : "+v"(a1), "+v"(b1));
            unsigned c0 = u[4], c1 = u[5], d0 = u[6], d1 = u[7];
            asm("v_permlane32_swap_b32 %0, %1" : "+v"(c0), "+v"(d0));
            asm("v_permlane32_swap_b32 %0, %1" : "+v"(c1), "+v"(d1));
            const u32x4 pb0 = { a0, a1, b0, b1 };
            const u32x4 pb1 = { c0, c1, d0, d1 };
            oacc = MFMA32(va0, __builtin_bit_cast(bf16x8, pb0), oacc);
            oacc = MFMA32(va1, __builtin_bit_cast(bf16x8, pb1), oacc);
        }
        // normalize + X write (row-sum lane-local; X region == own q region)
        const float l2 = lp + __shfl_xor(lp, 32);
        const float inv = 1.f / l2;
        // oacc regs r=0..7 hold d = (r&3) + 8*(r>>2) + 4*lh
        const u32x2 pkA = { cvt_pk(oacc[0] * inv, oacc[1] * inv),
                            cvt_pk(oacc[2] * inv, oacc[3] * inv) };
        *(u32x2*)(qs + qrow * 64 + ((h*16 + 4*lh) ^ ckey)) = pkA;
        const u32x2 pkB = { cvt_pk(oacc[4] * inv, oacc[5] * inv),
                            cvt_pk(oacc[6] * inv, oacc[7] * inv) };
        *(u32x2*)(qs + qrow * 64 + ((h*16 + 8 + 4*lh) ^ ckey)) = pkB;
    }
    __syncthreads();                            // X complete

    // ========== output projection: X[128x64] @ Wo + bo (frags from L2) =====
    const int xr = w * 16 + ll;
    const int xkey = (ll & 7) << 3;            // xr&7 == ll&7
    bf16x8 xf[2];
    #pragma unroll
    for (int k2 = 0; k2 < 2; ++k2)
        xf[k2] = *(const bf16x8*)(qs + xr * 64 + ((k2*32 + lq*8) ^ xkey));
    float* orow = out + ((size_t)b * 256 + half * 128 + xr) * kC;
    #pragma unroll
    for (int hmt = 0; hmt < 2; ++hmt) {        // 2 x 5 n-tiles: halves po regs
        f32x4 po[5];
        #pragma unroll
        for (int m5 = 0; m5 < 5; ++m5) po[m5] = (f32x4){0.f,0.f,0.f,0.f};
        #pragma unroll
        for (int k2 = 0; k2 < 2; ++k2)
            #pragma unroll
            for (int m5 = 0; m5 < 5; ++m5) {
                const int n = hmt * 80 + m5 * 16 + ll;
                po[m5] = MFMA16(*(const bf16x8*)(wto + n * 64 + k2*32 + lq*8),
                                xf[k2], po[m5]);
            }
        #pragma unroll
        for (int m5 = 0; m5 < 5; ++m5) {
            const int mt = hmt * 5 + m5;
            const int c0 = mt * 16 + 4 * lq;
            if (mt < 9) {
                const float4 bv4 = *(const float4*)(bo + c0);
                float4 o;
                o.x = po[m5][0] + bv4.x; o.y = po[m5][1] + bv4.y;
                o.z = po[m5][2] + bv4.z; o.w = po[m5][3] + bv4.w;
                *(float4*)(orow + c0) = o;
            } else {
                #pragma unroll
                for (int r = 0; r < 4; ++r) {
                    const int c = c0 + r;
                    if (c < kC) orow[c] = po[m5][r] + bo[c];
                }
            }
        }
    }
}

extern "C" void kernel_launch(void* const* d_in, const int* in_sizes, int n_in,
                              void* d_out, int out_size, void* d_ws, size_t ws_size,
                              hipStream_t stream) {
    const float* pose    = (const float*)d_in[0];
    const float* bpm_emb = (const float*)d_in[1];
    const float* Wq = (const float*)d_in[2];  const float* bq = (const float*)d_in[3];
    const float* Wk = (const float*)d_in[4];  const float* bk = (const float*)d_in[5];
    const float* Wv = (const float*)d_in[6];  const float* bv = (const float*)d_in[7];
    const float* Wb = (const float*)d_in[8];  const float* bb = (const float*)d_in[9];
    const float* Wo = (const float*)d_in[10]; const float* bo = (const float*)d_in[11];
    float* out = (float*)d_out;

    short* wt  = (short*)d_ws;                          // 81920 B
    float* kbc = (float*)((char*)d_ws + 81920);         // 65536 B

    prep_kernel<<<260, 128, 0, stream>>>(bpm_emb, Wq, Wk, Wv, Wb, bk, bb, Wo,
                                         wt, kbc);
    fused_kernel<<<512, 512, 0, stream>>>(pose, bq, bv, wt, kbc, bo, out);
}

// Round 9
// 129.834 us; speedup vs baseline: 1.7492x; 1.7492x over previous
//
#include <hip/hip_runtime.h>

constexpr int kC = 147, kH = 64, kBPM = 32;

typedef __attribute__((ext_vector_type(8)))  short bf16x8;   // MFMA A/B frag
typedef __attribute__((ext_vector_type(4)))  float f32x4;    // 16x16 C/D frag
typedef __attribute__((ext_vector_type(16))) float f32x16;   // 32x32 C/D frag
typedef __attribute__((ext_vector_type(2)))  unsigned u32x2;
typedef __attribute__((ext_vector_type(4)))  unsigned u32x4;

__device__ __forceinline__ short f2bf(float f) {             // RNE float->bf16
    unsigned u = __builtin_bit_cast(unsigned, f);
    u += 0x7fffu + ((u >> 16) & 1u);
    return (short)(u >> 16);
}
// Packed RNE f32x2 -> bf16x2 (single VALU op; bit-identical to f2bf pairs).
__device__ __forceinline__ unsigned cvt_pk(float lo, float hi) {
    unsigned r;
    asm("v_cvt_pk_bf16_f32 %0, %1, %2" : "=v"(r) : "v"(lo), "v"(hi));
    return r;
}
#define MFMA16(a,b,c) __builtin_amdgcn_mfma_f32_16x16x32_bf16((a),(b),(c),0,0,0)
#define MFMA32(a,b,c) __builtin_amdgcn_mfma_f32_32x32x16_bf16((a),(b),(c),0,0,0)

// Softmax in base 2: Wq and q-bias pre-scaled by 0.25*log2(e); P = 2^s.
#if __has_builtin(__builtin_amdgcn_exp2f)
  #define EXP2(x) __builtin_amdgcn_exp2f(x)
#else
  #define EXP2(x) __expf((x) * 0.6931471805599453f)   // exact: e^(x ln2) = 2^x
#endif
constexpr float kQScale = 0.25f * 1.4426950408889634f;

// LDS strides (shorts).
constexpr int WSS = 160;   // W qkv: [c][k], k=160 zero-padded (XOR-swizzled k)
constexpr int WOS = 72;    // Wo: [n][k], k=64 (XOR-swizzled k)

// LDS write-out of a prefetched W (values already scaled at load time).
// Thread map matches the coalesced load map: c = i&63, k-pair = i>>6.
__device__ __forceinline__ void stage_w_regs(const float* wr /*10*/,
                                             short* Ws, int tid) {
    #pragma unroll
    for (int it = 0; it < 5; ++it) {
        const int i = it * 1024 + tid;          // 5120 = 64c x 80 k-pairs
        const int c = i & 63, k = (i >> 6) * 2;
        *(unsigned*)&Ws[c * WSS + (k ^ (((c >> 3) & 3) << 3))]
            = cvt_pk(wr[2*it], wr[2*it + 1]);
    }
}

// One block per batch: 1024 threads = 16 waves = 4 waves/SIMD; LDS 160.5 KB.
// Single merged QKV stage: all three W matrices resident -> 60 MFMAs with 3
// independent acc chains, 3 barriers total.  qs/ks/vt XOR-swizzled:
// phys_col8granule = col ^ ((row&7)<<3)  (verified R8 layouts + attention).
__global__ __launch_bounds__(1024, 4) void fused_kernel(
    const float* __restrict__ pose, const float* __restrict__ bpm_emb,
    const float* __restrict__ Wq, const float* __restrict__ bq,
    const float* __restrict__ Wk, const float* __restrict__ bk,
    const float* __restrict__ Wv, const float* __restrict__ bv,
    const float* __restrict__ Wb, const float* __restrict__ bb,
    const float* __restrict__ Wo, const float* __restrict__ bo,
    float* __restrict__ out)
{
    __shared__ __align__(16) short Wqkv[3 * 64 * WSS];  // 61.4 KB; Wo overlay
    __shared__ __align__(16) short qs[256 * 64];        // 32 KB  q, later X
    __shared__ __align__(16) short ks_[256 * 64];       // 32 KB  k (+bias)
    __shared__ __align__(16) short vt[64 * 256];        // 32 KB  V^T: [d][j]
    __shared__ float bias_s[192];
    short* const Wqs = Wqkv;
    short* const Wks = Wqkv + 64 * WSS;
    short* const Wvs = Wqkv + 2 * 64 * WSS;
    short* const Wos = Wqkv;                 // Wo (11520 shorts), post-QKV

    const int tid = threadIdx.x;
    const int w = tid >> 6, lane = tid & 63;
    const int ll = lane & 15, lq = lane >> 4;
    const int lm = lane & 31, lh = lane >> 5;
    const int b = blockIdx.x;
    const size_t pbase = (size_t)b * 256 * kC;

    // ---- pose B-frags FIRST (block-exclusive data: start HBM latency now) --
    bf16x8 pf[5];
    {
        const int row = w * 16 + ll;
        const float* prow = pose + pbase + (size_t)row * kC;
        #pragma unroll
        for (int ksp = 0; ksp < 5; ++ksp) {
            const int c0 = ksp * 32 + lq * 8;
            float v[8];
            if (c0 + 8 <= kC) {
                const float4 f0 = *(const float4*)(prow + c0);
                const float4 f1 = *(const float4*)(prow + c0 + 4);
                v[0]=f0.x; v[1]=f0.y; v[2]=f0.z; v[3]=f0.w;
                v[4]=f1.x; v[5]=f1.y; v[6]=f1.z; v[7]=f1.w;
            } else {
                #pragma unroll
                for (int e = 0; e < 8; ++e) v[e] = (c0 + e < kC) ? prow[c0 + e] : 0.f;
            }
            const u32x4 t = { cvt_pk(v[0], v[1]), cvt_pk(v[2], v[3]),
                              cvt_pk(v[4], v[5]), cvt_pk(v[6], v[7]) };
            pf[ksp] = __builtin_bit_cast(bf16x8, t);
        }
    }
    // ---- all qkv weights -> regs (coalesced; L2-shared across blocks) ----
    {
        float wq_r[10], wk_r[10], wv_r[10];
        #pragma unroll
        for (int it = 0; it < 5; ++it) {
            const int i = it * 1024 + tid;
            const int c = i & 63, k = (i >> 6) * 2;
            const bool b0 = k < kC, b1 = k + 1 < kC;
            wq_r[2*it]   = b0 ? Wq[k * kH + c] * kQScale : 0.f;
            wq_r[2*it+1] = b1 ? Wq[(k + 1) * kH + c] * kQScale : 0.f;
            wk_r[2*it]   = b0 ? Wk[k * kH + c] : 0.f;
            wk_r[2*it+1] = b1 ? Wk[(k + 1) * kH + c] : 0.f;
            wv_r[2*it]   = b0 ? Wv[k * kH + c] : 0.f;
            wv_r[2*it+1] = b1 ? Wv[(k + 1) * kH + c] : 0.f;
        }
        // ---- combined biases (q-bias pre-scaled by kQScale) ----
        if (tid < 192) {
            const int m = tid >> 6, c = tid & 63;
            float a = ((m == 0) ? bq : (m == 1) ? bk : bv)[c];
            if (m == 1) {
                a += bb[c];
                #pragma unroll
                for (int k2 = 0; k2 < kBPM; ++k2)
                    a = fmaf(bpm_emb[b * kBPM + k2], Wb[k2 * kH + c], a);
            }
            if (m == 0) a *= kQScale;
            bias_s[tid] = a;
        }
        stage_w_regs(wq_r, Wqs, tid);
        stage_w_regs(wk_r, Wks, tid);
        stage_w_regs(wv_r, Wvs, tid);
    }
    __syncthreads();                            // all W resident

    // ============ merged QKV: 60 MFMAs, 3 independent acc chains ==========
    f32x4 aQ[4], aK[4], aV[4];
    #pragma unroll
    for (int mt = 0; mt < 4; ++mt) {
        aQ[mt] = (f32x4){0.f,0.f,0.f,0.f};
        aK[mt] = (f32x4){0.f,0.f,0.f,0.f};
        aV[mt] = (f32x4){0.f,0.f,0.f,0.f};
    }
    #pragma unroll
    for (int ksp = 0; ksp < 5; ++ksp)
        #pragma unroll
        for (int mt = 0; mt < 4; ++mt) {
            const int c = mt * 16 + ll;
            const int ko = (ksp*32 + lq*8) ^ (((c >> 3) & 3) << 3);
            aQ[mt] = MFMA16(*(const bf16x8*)(Wqs + c * WSS + ko), pf[ksp], aQ[mt]);
            aK[mt] = MFMA16(*(const bf16x8*)(Wks + c * WSS + ko), pf[ksp], aK[mt]);
            aV[mt] = MFMA16(*(const bf16x8*)(Wvs + c * WSS + ko), pf[ksp], aV[mt]);
        }
    // epilogue: D row = out-col mt*16+4lq+r, D col = pose-row w*16+ll
    {
        const int row = w * 16 + ll;
        const int rkey = (ll & 7) << 3;         // row&7 == ll&7
        #pragma unroll
        for (int mt = 0; mt < 4; ++mt) {
            const int c0 = mt * 16 + 4 * lq;
            const float4 bq4 = *(const float4*)&bias_s[0 * kH + c0];
            const u32x2 pq = { cvt_pk(aQ[mt][0] + bq4.x, aQ[mt][1] + bq4.y),
                               cvt_pk(aQ[mt][2] + bq4.z, aQ[mt][3] + bq4.w) };
            *(u32x2*)(qs + row * 64 + (c0 ^ rkey)) = pq;
            const float4 bk4 = *(const float4*)&bias_s[1 * kH + c0];
            const u32x2 pk = { cvt_pk(aK[mt][0] + bk4.x, aK[mt][1] + bk4.y),
                               cvt_pk(aK[mt][2] + bk4.z, aK[mt][3] + bk4.w) };
            *(u32x2*)(ks_ + row * 64 + (c0 ^ rkey)) = pk;
            const float4 bv4 = *(const float4*)&bias_s[2 * kH + c0];
            vt[(c0 + 0) * 256 + (row ^ (((c0 + 0) & 7) << 3))] = f2bf(aV[mt][0] + bv4.x);
            vt[(c0 + 1) * 256 + (row ^ (((c0 + 1) & 7) << 3))] = f2bf(aV[mt][1] + bv4.y);
            vt[(c0 + 2) * 256 + (row ^ (((c0 + 2) & 7) << 3))] = f2bf(aV[mt][2] + bv4.z);
            vt[(c0 + 3) * 256 + (row ^ (((c0 + 3) & 7) << 3))] = f2bf(aV[mt][3] + bv4.w);
        }
    }
    // ---- T14: Wo -> regs now; staged right after the barrier ----
    float wo_r[10];
    #pragma unroll
    for (int it = 0; it < 5; ++it) {
        const int i = it * 1024 + tid;          // 5120 = 160n x 32 k-pairs
        const int n = i % 160, k = (i / 160) * 2;
        wo_r[2*it]   = (n < kC) ? Wo[k * kC + n] : 0.f;
        wo_r[2*it+1] = (n < kC) ? Wo[(k + 1) * kC + n] : 0.f;
    }
    __syncthreads();                            // qs/ks/vt complete; W dead

    // ---- stage Wo^T[n][k] into dead W region (read after next barrier) ----
    #pragma unroll
    for (int it = 0; it < 5; ++it) {
        const int i = it * 1024 + tid;
        const int n = i % 160, k = (i / 160) * 2;
        *(unsigned*)&Wos[n * WOS + (k ^ (((n >> 3) & 3) << 3))]
            = cvt_pk(wo_r[2*it], wo_r[2*it + 1]);
    }

    // ================= attention: wave = (head, q-quarter of 64) ===========
    // Swapped QK^T (lane = q) + permlane half-exchange: P stays in registers;
    // PV = 32x32x16 MFMA with B=P (col=q=lane).  s32-outer caps live regs.
    const int h = w & 3;
    const int q0 = (w >> 2) * 64;
    const int vrow = h * 16 + (lm & 15);       // lanes 16-31 dup rows (bcast)
    const int vkey = (vrow & 7) << 3;
    const int ckey = (lm & 7) << 3;            // q/k rows ≡ lm (mod 8)
    const f32x16 z16 = {0.f,0.f,0.f,0.f,0.f,0.f,0.f,0.f,
                        0.f,0.f,0.f,0.f,0.f,0.f,0.f,0.f};

    #pragma unroll
    for (int s32 = 0; s32 < 2; ++s32) {
        const int qrow = q0 + s32 * 32 + lm;   // qrow&7 == lm&7
        const bf16x8 qf = *(const bf16x8*)(qs + qrow * 64 + ((h*16 + lh*8) ^ ckey));
        f32x16 oacc = z16;
        float lp = 0.f;
        #pragma unroll 2
        for (int jb = 0; jb < 8; ++jb) {
            const int j0 = jb * 32;
            const bf16x8 kf  = *(const bf16x8*)(ks_ + (j0 + lm) * 64 + ((h*16 + lh*8) ^ ckey));
            const bf16x8 va0 = *(const bf16x8*)(vt + vrow * 256 + ((j0 + lh*8) ^ vkey));
            const bf16x8 va1 = *(const bf16x8*)(vt + vrow * 256 + ((j0 + 16 + lh*8) ^ vkey));
            const f32x16 s = MFMA32(kf, qf, z16);    // S^T: col=q=lm, row=j
            float sum = 0.f;
            unsigned u[8];
            #pragma unroll
            for (int g = 0; g < 4; ++g) {            // j = r + 8g + 4lh
                const float p0 = EXP2(s[4*g + 0]);   // scale folded into Wq
                const float p1 = EXP2(s[4*g + 1]);
                const float p2 = EXP2(s[4*g + 2]);
                const float p3 = EXP2(s[4*g + 3]);
                sum += (p0 + p1) + (p2 + p3);
                u[2*g]   = cvt_pk(p0, p1);
                u[2*g+1] = cvt_pk(p2, p3);
            }
            lp += sum;
            // lane±32 half-exchange -> B-frags with k=j in order (T12)
            unsigned a0 = u[0], a1 = u[1], b0 = u[2], b1 = u[3];
            asm("v_permlane32_swap_b32 %0, %1" : "+v"(a0), "+v"(b0));
            asm("v_permlane32_swap_b32 %0, %1" : "+v"(a1), "+v"(b1));
            unsigned c0 = u[4], c1 = u[5], d0 = u[6], d1 = u[7];
            asm("v_permlane32_swap_b32 %0, %1" : "+v"(c0), "+v"(d0));
            asm("v_permlane32_swap_b32 %0, %1" : "+v"(c1), "+v"(d1));
            const u32x4 pb0 = { a0, a1, b0, b1 };
            const u32x4 pb1 = { c0, c1, d0, d1 };
            oacc = MFMA32(va0, __builtin_bit_cast(bf16x8, pb0), oacc);
            oacc = MFMA32(va1, __builtin_bit_cast(bf16x8, pb1), oacc);
        }
        // normalize + X write (row-sum lane-local; X region == own q region)
        const float l2 = lp + __shfl_xor(lp, 32);
        const float inv = 1.f / l2;
        // oacc regs r=0..7 hold d = (r&3) + 8*(r>>2) + 4*lh
        const u32x2 pkA = { cvt_pk(oacc[0] * inv, oacc[1] * inv),
                            cvt_pk(oacc[2] * inv, oacc[3] * inv) };
        *(u32x2*)(qs + qrow * 64 + ((h*16 + 4*lh) ^ ckey)) = pkA;
        const u32x2 pkB = { cvt_pk(oacc[4] * inv, oacc[5] * inv),
                            cvt_pk(oacc[6] * inv, oacc[7] * inv) };
        *(u32x2*)(qs + qrow * 64 + ((h*16 + 8 + 4*lh) ^ ckey)) = pkB;
    }
    __syncthreads();                            // X complete; Wo staged

    // ================= output projection: X[256x64] @ Wo + bo ==============
    const int xr = w * 16 + ll;
    const int xkey = (ll & 7) << 3;            // xr&7 == ll&7
    bf16x8 xf[2];
    #pragma unroll
    for (int k2 = 0; k2 < 2; ++k2)
        xf[k2] = *(const bf16x8*)(qs + xr * 64 + ((k2*32 + lq*8) ^ xkey));

    f32x4 po[10];
    #pragma unroll
    for (int mt = 0; mt < 10; ++mt) po[mt] = (f32x4){0.f,0.f,0.f,0.f};
    #pragma unroll
    for (int k2 = 0; k2 < 2; ++k2)
        #pragma unroll
        for (int mt = 0; mt < 10; ++mt) {
            const int n = mt * 16 + ll;
            const int key = ((n >> 3) & 3) << 3;
            const bf16x8 wf = *(const bf16x8*)(Wos + n * WOS + ((k2*32 + lq*8) ^ key));
            po[mt] = MFMA16(wf, xf[k2], po[mt]);
        }
    {
        float* orow = out + ((size_t)b * 256 + xr) * kC;
        #pragma unroll
        for (int mt = 0; mt < 10; ++mt) {
            const int c0 = mt * 16 + 4 * lq;
            if (mt < 9) {
                const float4 bv4 = *(const float4*)(bo + c0);
                float4 o;
                o.x = po[mt][0] + bv4.x; o.y = po[mt][1] + bv4.y;
                o.z = po[mt][2] + bv4.z; o.w = po[mt][3] + bv4.w;
                *(float4*)(orow + c0) = o;
            } else {
                #pragma unroll
                for (int r = 0; r < 4; ++r) {
                    const int c = c0 + r;
                    if (c < kC) orow[c] = po[mt][r] + bo[c];
                }
            }
        }
    }
}

extern "C" void kernel_launch(void* const* d_in, const int* in_sizes, int n_in,
                              void* d_out, int out_size, void* d_ws, size_t ws_size,
                              hipStream_t stream) {
    const float* pose    = (const float*)d_in[0];
    const float* bpm_emb = (const float*)d_in[1];
    const float* Wq = (const float*)d_in[2];  const float* bq = (const float*)d_in[3];
    const float* Wk = (const float*)d_in[4];  const float* bk = (const float*)d_in[5];
    const float* Wv = (const float*)d_in[6];  const float* bv = (const float*)d_in[7];
    const float* Wb = (const float*)d_in[8];  const float* bb = (const float*)d_in[9];
    const float* Wo = (const float*)d_in[10]; const float* bo = (const float*)d_in[11];
    float* out = (float*)d_out;

    fused_kernel<<<256, 1024, 0, stream>>>(
        pose, bpm_emb, Wq, bq, Wk, bk, Wv, bv, Wb, bb, Wo, bo, out);
}